// Round 1
// baseline (97.979 us; speedup 1.0000x reference)
//
#include <hip/hip_runtime.h>

#define N_LATENT 128
#define N_OUT    128
#define CAP      1024   // max samples per donor-block list (mean 32.8, ~30 sigma headroom)

__global__ __launch_bounds__(256, 2) void ldz_kernel(
    const float* __restrict__ u,
    const int*   __restrict__ donor_id,
    const float* __restrict__ amat,
    const float* __restrict__ offsets,
    float*       __restrict__ out,
    int B)
{
    const int d = blockIdx.x;
    const int t = threadIdx.x;
    const int h = t >> 7;    // which half of the latent dim this thread accumulates
    const int o = t & 127;   // output column

    __shared__ int   slist[CAP];
    __shared__ int   scount;
    __shared__ float redbuf[2][2][N_OUT];  // [parity][sample-slot][o]

    if (t == 0) scount = 0;
    __syncthreads();

    // ---- Phase 1: compact this donor's sample indices into LDS ----
    for (int base = t; base < B; base += 256) {
        if (donor_id[base] == d) {
            int pos = atomicAdd(&scount, 1);
            if (pos < CAP) slist[pos] = base;
        }
    }
    __syncthreads();
    int n = scount;
    if (n > CAP) n = CAP;

    // ---- Phase 2: stage A[d] into registers ----
    // thread (h,o) holds A[l][o] for l in [h*64, h*64+64)
    float areg[64];
    const float* abase = amat + ((size_t)d * N_LATENT + (size_t)h * 64) * N_OUT + o;
    #pragma unroll
    for (int i = 0; i < 64; ++i) areg[i] = abase[(size_t)i * N_OUT];

    const float off_reg = offsets[(size_t)d * N_OUT + o];

    // ---- Phase 3: per-sample matvec, 2 samples per iteration ----
    for (int s0 = 0; s0 < n; s0 += 2) {
        const int  pbuf = (s0 >> 1) & 1;
        const bool has1 = (s0 + 1 < n);
        int b0 = __builtin_amdgcn_readfirstlane(slist[s0]);
        int b1 = __builtin_amdgcn_readfirstlane(has1 ? slist[s0 + 1] : slist[s0]);

        const float* u0 = u + (size_t)b0 * N_LATENT + h * 64;
        const float* u1 = u + (size_t)b1 * N_LATENT + h * 64;

        float acc0 = 0.f, acc1 = 0.f;
        #pragma unroll
        for (int i = 0; i < 64; ++i) {
            acc0 = fmaf(u0[i], areg[i], acc0);
            acc1 = fmaf(u1[i], areg[i], acc1);
        }

        if (h == 1) {
            redbuf[pbuf][0][o] = acc0;
            redbuf[pbuf][1][o] = acc1;
        }
        __syncthreads();
        if (h == 0) {
            float t0 = acc0 + redbuf[pbuf][0][o];
            float t1 = acc1 + redbuf[pbuf][1][o];
            out[(size_t)b0 * N_OUT + o] = u[(size_t)b0 * N_LATENT + o] + off_reg + t0;
            if (has1)
                out[(size_t)b1 * N_OUT + o] = u[(size_t)b1 * N_LATENT + o] + off_reg + t1;
        }
        // double-buffered redbuf: one barrier per iteration is sufficient
    }
}

extern "C" void kernel_launch(void* const* d_in, const int* in_sizes, int n_in,
                              void* d_out, int out_size, void* d_ws, size_t ws_size,
                              hipStream_t stream) {
    const float* u        = (const float*)d_in[0];
    const int*   donor_id = (const int*)d_in[1];
    const float* amat     = (const float*)d_in[2];
    const float* offsets  = (const float*)d_in[3];
    float*       out      = (float*)d_out;

    const int B        = in_sizes[1];           // 16384 samples
    const int n_donors = in_sizes[3] / N_OUT;   // 500

    hipLaunchKernelGGL(ldz_kernel, dim3(n_donors), dim3(256), 0, stream,
                       u, donor_id, amat, offsets, out, B);
}

// Round 2
// 54.859 us; speedup vs baseline: 1.7860x; 1.7860x over previous
//
#include <hip/hip_runtime.h>

#define N_LATENT 128
#define N_OUT    128
#define CAP      128   // per-(donor,parity) sample capacity; mean ~16.4, huge headroom

__global__ __launch_bounds__(128, 2) void ldz_kernel(
    const float* __restrict__ u,
    const int*   __restrict__ donor_id,
    const float* __restrict__ amat,
    const float* __restrict__ offsets,
    float*       __restrict__ out,
    int B)
{
    const int d   = blockIdx.x >> 1;   // 2 blocks per donor
    const int par = blockIdx.x & 1;    // sample-index parity this block owns
    const int o   = threadIdx.x;       // output column, 0..127

    __shared__ int slist[CAP];
    __shared__ int scount;
    if (o == 0) scount = 0;
    __syncthreads();

    // ---- Issue A-column loads FIRST so their latency overlaps the scan ----
    // Thread o holds the full column A[d][:][o] in VGPRs.
    float a[N_LATENT];
    const float* ab = amat + (size_t)d * N_LATENT * N_OUT + o;
    #pragma unroll
    for (int l = 0; l < N_LATENT; ++l) a[l] = ab[(size_t)l * N_OUT];

    // ---- Scan donor ids (int4-vectorized), compact parity-matching samples ----
    const int4* did4 = (const int4*)donor_id;
    const int nq = B >> 2;
    #pragma unroll 4
    for (int i = o; i < nq; i += 128) {
        int4 v = did4[i];
        int b = 4 * i;
        if (v.x == d && ((b + 0) & 1) == par) { int p = atomicAdd(&scount, 1); if (p < CAP) slist[p] = b + 0; }
        if (v.y == d && ((b + 1) & 1) == par) { int p = atomicAdd(&scount, 1); if (p < CAP) slist[p] = b + 1; }
        if (v.z == d && ((b + 2) & 1) == par) { int p = atomicAdd(&scount, 1); if (p < CAP) slist[p] = b + 2; }
        if (v.w == d && ((b + 3) & 1) == par) { int p = atomicAdd(&scount, 1); if (p < CAP) slist[p] = b + 3; }
    }

    // ---- Pin A in VGPRs: empty asm reads+writes each element, so the
    // compiler cannot sink/remat the loads into the sample loop (R1's bug:
    // VGPR_Count=44 showed A was being re-loaded per sample). ----
    #pragma unroll
    for (int l = 0; l < N_LATENT; ++l) asm volatile("" : "+v"(a[l]));

    const float off = offsets[(size_t)d * N_OUT + o];

    __syncthreads();
    int n = scount; if (n > CAP) n = CAP;

    // ---- Per-sample matvec: 2 samples in flight, 2 accum chains each ----
    for (int s = 0; s < n; s += 2) {
        const bool has1 = (s + 1 < n);
        int b0 = __builtin_amdgcn_readfirstlane(slist[s]);
        int b1 = __builtin_amdgcn_readfirstlane(slist[has1 ? s + 1 : s]);
        const float* u0 = u + (size_t)b0 * N_LATENT;  // wave-uniform base -> s_load
        const float* u1 = u + (size_t)b1 * N_LATENT;

        float a00 = 0.f, a01 = 0.f, a10 = 0.f, a11 = 0.f;
        #pragma unroll
        for (int l = 0; l < N_LATENT; l += 2) {
            a00 = fmaf(u0[l],     a[l],     a00);
            a01 = fmaf(u0[l + 1], a[l + 1], a01);
            a10 = fmaf(u1[l],     a[l],     a10);
            a11 = fmaf(u1[l + 1], a[l + 1], a11);
        }
        out[(size_t)b0 * N_OUT + o] = u0[o] + off + a00 + a01;
        if (has1)
            out[(size_t)b1 * N_OUT + o] = u1[o] + off + a10 + a11;
    }
}

extern "C" void kernel_launch(void* const* d_in, const int* in_sizes, int n_in,
                              void* d_out, int out_size, void* d_ws, size_t ws_size,
                              hipStream_t stream) {
    const float* u        = (const float*)d_in[0];
    const int*   donor_id = (const int*)d_in[1];
    const float* amat     = (const float*)d_in[2];
    const float* offsets  = (const float*)d_in[3];
    float*       out      = (float*)d_out;

    const int B        = in_sizes[1];           // 16384
    const int n_donors = in_sizes[3] / N_OUT;   // 500

    hipLaunchKernelGGL(ldz_kernel, dim3(n_donors * 2), dim3(128), 0, stream,
                       u, donor_id, amat, offsets, out, B);
}